// Round 1
// baseline (447.184 us; speedup 1.0000x reference)
//
#include <hip/hip_runtime.h>
#include <float.h>
#include <math.h>

// Problem constants: query (8,512,64,64) f32, keys (2000,512) f32
constexpr int D_  = 512;
constexpr int HW_ = 4096;           // 64*64
constexpr int N_  = 32768;          // B*HW
constexpr int M_  = 2000;
constexpr int MP_ = 2048;           // padded key count

// fp8 now stores RAW q (no pre-normalization, no scale): e4m3 relative error is
// scale-invariant, and rnorm is folded into the score at fold time instead.

typedef int          i32x8  __attribute__((ext_vector_type(8)));
typedef float        f32x16 __attribute__((ext_vector_type(16)));
typedef unsigned int uu32x4 __attribute__((ext_vector_type(4)));
typedef unsigned int uu32x2 __attribute__((ext_vector_type(2)));

__device__ inline unsigned umn(unsigned a, unsigned b) { return a < b ? a : b; }
__device__ inline unsigned umx(unsigned a, unsigned b) { return a > b ? a : b; }

// single-instruction unsigned median-of-3 (VOP3, gfx9+)
__device__ inline unsigned med3u(unsigned a, unsigned b, unsigned c) {
    unsigned d;
    asm("v_med3_u32 %0, %1, %2, %3" : "=v"(d) : "v"(a), "v"(b), "v"(c));
    return d;
}

// pack 4 floats -> 4 OCP e4m3 bytes (v_cvt_pk_fp8_f32; OCP format on gfx950)
__device__ inline unsigned pk4f8(float a, float b, float c, float d) {
    int v = 0;
    v = __builtin_amdgcn_cvt_pk_fp8_f32(a, b, v, false);   // bytes 0-1
    v = __builtin_amdgcn_cvt_pk_fp8_f32(c, d, v, true);    // bytes 2-3
    return (unsigned)v;
}

// ---------------- kernel 1: SINGLE-PASS rnorm + fp8 A-fragment swizzle ----------------
// qsw8 holds raw q in e4m3, 32x32x64-A-fragment order:
// frag (pb32, kc64): lane L byte j  <->  A[m = pb*32 + (L&31)][k = kc*64 + (L>>5)*32 + j]
// Sum-of-squares accumulates in registers during the same tile loads that feed the
// fp8 emit -> query is read from HBM exactly once (was twice).
__global__ __launch_bounds__(256) void k_prep(const float* __restrict__ q,
                                              float* __restrict__ rnorm,
                                              unsigned char* __restrict__ qsw8) {
    __shared__ float  tile[64][65];
    __shared__ float4 part2[16][17];
    int t = threadIdx.x;
    int p0 = blockIdx.x * 64;                    // 64 | 4096 -> single batch per block
    const float* base = q + (size_t)(p0 / HW_) * (D_ * HW_) + (p0 % HW_);
    int pb0 = blockIdx.x * 2;                    // pb32 base (2 per block)

    float s0 = 0.f, s1 = 0.f, s2 = 0.f, s3 = 0.f;  // sumsq partials for px quad (t&15)*4
    for (int ct = 0; ct < 8; ++ct) {             // kc64 = ct
        if (ct) __syncthreads();                 // prev emit done before tile overwrite
#pragma unroll
        for (int i = 0; i < 4; ++i) {
            int sl = t + 256 * i;                // 1024 float4 slots: 64 ch-rows x 16
            int row = sl >> 4, p4 = (sl & 15) * 4;
            float4 v = *(const float4*)(base + (size_t)(ct * 64 + row) * HW_ + p4);
            s0 += v.x * v.x; s1 += v.y * v.y; s2 += v.z * v.z; s3 += v.w * v.w;
            tile[row][p4 + 0] = v.x; tile[row][p4 + 1] = v.y;
            tile[row][p4 + 2] = v.z; tile[row][p4 + 3] = v.w;
        }
        __syncthreads();
        {
            // 256 slots: 2 pb-frags x 64 lanes x 2 16B-halves
            int pbi = t >> 7, L = (t >> 1) & 63, hf = t & 1;
            int plx = pbi * 32 + (L & 31);
            int cl  = (L >> 5) * 32 + hf * 16;
            unsigned d[4];
#pragma unroll
            for (int w4 = 0; w4 < 4; ++w4)
                d[w4] = pk4f8(tile[cl + w4 * 4 + 0][plx],
                              tile[cl + w4 * 4 + 1][plx],
                              tile[cl + w4 * 4 + 2][plx],
                              tile[cl + w4 * 4 + 3][plx]);
            *(uu32x4*)(qsw8 + (((size_t)(pb0 + pbi) * 8 + ct) * 64 + L) * 32 + hf * 16)
                = (uu32x4){d[0], d[1], d[2], d[3]};
        }
    }
    // reduce sumsq: thread t held px quad (t&15)*4 over ch rows {t>>4 + 16i + 64ct}
    part2[t & 15][t >> 4] = make_float4(s0, s1, s2, s3);
    __syncthreads();
    if (t < 64) {
        float ss = 0.f;
#pragma unroll
        for (int g = 0; g < 16; ++g)
            ss += ((const float*)&part2[t >> 2][g])[t & 3];
        rnorm[p0 + t] = 1.0f / fmaxf(sqrtf(ss), 1e-12f);   // matches F.normalize eps
    }
}

// ---------------- kernel 2: fused |k|^2 + fp8 B-fragment swizzle (unchanged) ----------------
// frag (nb32, kc64): lane L byte j <-> B[k = kc*64 + (L>>5)*32 + j][n = nb*32 + (L&31)]
__global__ __launch_bounds__(256) void k_keys(const float* __restrict__ keys,
                                              float* __restrict__ kn,
                                              unsigned char* __restrict__ ksw8) {
    int wave = threadIdx.x >> 6;
    int lane = threadIdx.x & 63;
    int m = blockIdx.x * 4 + wave;               // grid 512 -> m in [0,2048)
    int kc = lane >> 3, sub = lane & 7;
    int kh = sub >> 2, bg = sub & 3;
    int c = kc * 64 + kh * 32 + bg * 8;          // 8 channels per lane, covers all 512
    float4 v0 = make_float4(0.f, 0.f, 0.f, 0.f);
    float4 v1 = make_float4(0.f, 0.f, 0.f, 0.f);
    if (m < M_) {
        const float* row = keys + (size_t)m * D_ + c;
        v0 = *(const float4*)(row);
        v1 = *(const float4*)(row + 4);
    }
    float s = v0.x * v0.x + v0.y * v0.y + v0.z * v0.z + v0.w * v0.w
            + v1.x * v1.x + v1.y * v1.y + v1.z * v1.z + v1.w * v1.w;
    for (int off = 32; off; off >>= 1) s += __shfl_down(s, off, 64);
    if (lane == 0) kn[m] = (m < M_) ? s : FLT_MAX;
    unsigned d0 = pk4f8(v0.x, v0.y, v0.z, v0.w);
    unsigned d1 = pk4f8(v1.x, v1.y, v1.z, v1.w);
    *(uu32x2*)(ksw8 + (((size_t)(m >> 5) * 8 + kc) * 64 + kh * 32 + (m & 31)) * 32 + bg * 8)
        = (uu32x2){d0, d1};
}

// insert (t,j) into sorted top-3 (s1<=s2<=s3) with index tie-break
__device__ inline void insert3(float& s1, unsigned& i1, float& s2, unsigned& i2,
                               float& s3, unsigned& i3, float t, unsigned j) {
    if (t < s1 || (t == s1 && j < i1))      { s3 = s2; i3 = i2; s2 = s1; i2 = i1; s1 = t; i1 = j; }
    else if (t < s2 || (t == s2 && j < i2)) { s3 = s2; i3 = i2; s2 = t; i2 = j; }
    else if (t < s3 || (t == s3 && j < i3)) { s3 = t; i3 = j; }
}

// ---------------- kernel 3: fp8 MX MFMA score GEMM (32x32x64, scales = 1.0) ----------------
// v2: chunk-boundary WAR hazard removed. Each chunk's accumulator starts as a FRESH def
// (acc = mfma(A,B,0) — no explicit reset), and the previous chunk's fold is interleaved
// per-ni between the kc=0 MFMA issues. The scheduler can rename acc (partial dbuf) and
// keep the MFMA pipe fed during fold VALU. Fold is 5 ops/score via v_med3_u32 insert.
// Score s = kn - 2*rnorm[pix]*acc (rnorm folded here since fp8 holds raw q); positive
// for this data -> float bits compare as unsigned. 10-bit id in low mantissa as before.
__global__ __launch_bounds__(256, 2) void k_mfma(const unsigned char* __restrict__ qsw8,
                                                 const unsigned char* __restrict__ ksw8,
                                                 const float* __restrict__ kn,
                                                 const float* __restrict__ rnorm,
                                                 float4* __restrict__ best12,
                                                 float2* __restrict__ best3) {
    __shared__ float kns[1024];
    __shared__ float rns[128];
    int t = threadIdx.x;
    int lane = t & 63;
    int wr = __builtin_amdgcn_readfirstlane(t >> 6);   // pixel-row group 0..3
    int colk = lane & 31, h = lane >> 5;
    int p0 = blockIdx.x * 128;
    int yb = blockIdx.y;                               // key half: yb*1024
#pragma unroll
    for (int i = 0; i < 4; ++i) kns[t + 256 * i] = kn[yb * 1024 + t + 256 * i];
    if (t < 128) rns[t] = rnorm[p0 + t];
    __syncthreads();

    // per-lane fold factors: fr[r] = -2*rnorm[pixel(r,h)] (32x32 C/D row map)
    float fr[16];
#pragma unroll
    for (int r = 0; r < 16; ++r)
        fr[r] = -2.0f * rns[wr * 32 + (r & 3) + 8 * (r >> 2) + 4 * h];

    // lane-resolved fragment bases (bytes). A(kc) = aq + kc*2048;
    // B(ni,ch,kc) = bk + ((ch*4+ni)*8 + kc)*2048
    const unsigned char* aq = qsw8 + ((size_t)(blockIdx.x * 4 + wr) * 8) * 2048 + lane * 32;
    const unsigned char* bk = ksw8 + ((size_t)(yb * 32) * 8) * 2048 + lane * 32;

    unsigned pk1[16], pk2[16], pk3[16];
#pragma unroll
    for (int i = 0; i < 16; ++i) { pk1[i] = 0xFFFFFFFFu; pk2[i] = 0xFFFFFFFFu; pk3[i] = 0xFFFFFFFFu; }

    f32x16 acc[4];
    int scl = 0x7F7F7F7F;                        // e8m0 = 127 -> x1.0 in every byte/lane

    // fold chunk chf's scores for sub-block ni into the running top-3.
    // med3 insert: s1'=min(s1,p); s2'=med3(s1,s2,p); s3'=med3(s2,s3,p)  (reads before writes)
    auto fold = [&](int chf, int ni) {
        float kc4 = kns[chf * 128 + ni * 32 + colk];
        unsigned idbase = ((unsigned)(chf * 4 + ni) << 5) | (unsigned)colk;
#pragma unroll
        for (int r = 0; r < 16; ++r) {
            float sc = fmaf(fr[r], acc[ni][r], kc4);
            unsigned p = (__float_as_uint(sc) & ~1023u) | idbase;
            unsigned n3 = med3u(pk2[r], pk3[r], p);
            unsigned n2 = med3u(pk1[r], pk2[r], p);
            pk1[r] = umn(pk1[r], p);
            pk2[r] = n2;
            pk3[r] = n3;
        }
    };

    i32x8 curA, nxtA, curB[4], nxtB[4];
    curA = *(const i32x8*)(aq);
#pragma unroll
    for (int ni = 0; ni < 4; ++ni) curB[ni] = *(const i32x8*)(bk + (size_t)(ni * 8) * 2048);

#pragma unroll 1
    for (int ch = 0; ch < 8; ++ch) {
#pragma unroll
        for (int kc = 0; kc < 8; ++kc) {
            // prefetch step (ch,kc)+1
            int kcn = (kc + 1) & 7;
            int chn = ch + (kc == 7 ? 1 : 0);
            if (kc < 7 || ch < 7) {
                nxtA = *(const i32x8*)(aq + (size_t)kcn * 2048);
#pragma unroll
                for (int ni = 0; ni < 4; ++ni)
                    nxtB[ni] = *(const i32x8*)(bk + (size_t)((chn * 4 + ni) * 8 + kcn) * 2048);
            }
            if (kc == 0) {
                // chunk start: fold prev chunk per-ni, then FRESH-DEF mfma (C = 0)
#pragma unroll
                for (int ni = 0; ni < 4; ++ni) {
                    if (ch) fold(ch - 1, ni);
                    f32x16 z;
#pragma unroll
                    for (int r = 0; r < 16; ++r) z[r] = 0.f;
                    acc[ni] = __builtin_amdgcn_mfma_scale_f32_32x32x64_f8f6f4(
                        curA, curB[ni], z, 0, 0, 0, scl, 0, scl);
                }
            } else {
#pragma unroll
                for (int ni = 0; ni < 4; ++ni)
                    acc[ni] = __builtin_amdgcn_mfma_scale_f32_32x32x64_f8f6f4(
                        curA, curB[ni], acc[ni], 0, 0, 0, scl, 0, scl);
            }
            curA = nxtA;
#pragma unroll
            for (int ni = 0; ni < 4; ++ni) curB[ni] = nxtB[ni];
        }
    }
#pragma unroll
    for (int ni = 0; ni < 4; ++ni) fold(7, ni);   // last chunk

    // ---- epilogue: packed-list butterfly over the 32 colk lanes; writers store top-3 ----
#pragma unroll
    for (int r = 0; r < 16; ++r) {
        unsigned a1 = pk1[r], a2 = pk2[r], a3 = pk3[r];
#pragma unroll
        for (int mask = 1; mask < 32; mask <<= 1) {
            unsigned b1 = (unsigned)__shfl_xor((int)a1, mask, 64);
            unsigned b2 = (unsigned)__shfl_xor((int)a2, mask, 64);
            unsigned b3 = (unsigned)__shfl_xor((int)a3, mask, 64);
            unsigned x1 = umn(a1, b1), y1 = umx(a1, b1);
            unsigned x2 = umn(a2, b2);
            unsigned z  = umn(a3, b3);
            a1 = x1;
            a2 = umn(y1, x2);
            a3 = umn(umx(y1, x2), z);
        }
        if (colk == 0) {
            int pix = wr * 32 + (r & 3) + 8 * (r >> 2) + 4 * h;   // 32x32 C/D row map
            // unpack: score (trunc) + global key index
            unsigned l1 = a1 & 1023u, l2 = a2 & 1023u, l3 = a3 & 1023u;
            unsigned m1 = (unsigned)(yb * 1024) + (l1 >> 7) * 128 + ((l1 >> 5) & 3) * 32 + (l1 & 31);
            unsigned m2 = (unsigned)(yb * 1024) + (l2 >> 7) * 128 + ((l2 >> 5) & 3) * 32 + (l2 & 31);
            unsigned m3 = (unsigned)(yb * 1024) + (l3 >> 7) * 128 + ((l3 >> 5) & 3) * 32 + (l3 & 31);
            size_t o = (size_t)yb * N_ + p0 + pix;
            best12[o] = make_float4(__uint_as_float(a1 & ~1023u), __uint_as_float(m1),
                                    __uint_as_float(a2 & ~1023u), __uint_as_float(m2));
            best3[o]  = make_float2(__uint_as_float(a3 & ~1023u), __uint_as_float(m3));
        }
    }
}

// ---------------- kernel 4: merge 6 cands -> approx-top-3, exact fp32 rescue + heatmap ----------------
// Block = 64 pixels x 4 c-groups (256 thr). Reads fp32 q (NOT fp8): rescue must be exact.
__global__ __launch_bounds__(256) void k_heat(
    const float* __restrict__ q, const float* __restrict__ keys,
    const float* __restrict__ kn, const float* __restrict__ rnorm,
    const float4* __restrict__ best12, const float2* __restrict__ best3,
    float* __restrict__ out)
{
    __shared__ float4 pA[64][5];                 // (d0,d1,d2,h0) x 4 cg (+1 pad)
    __shared__ float4 pB[64][5];                 // (h1,h2,-,-)
    int t = threadIdx.x;
    int pl = t & 63, cg = t >> 6;
    int p0 = blockIdx.x * 64;
    int p = p0 + pl;
    const float* qb = q + (size_t)(p / HW_) * (D_ * HW_) + (p % HW_);

    // gather the 2 halves' top-3 lists, merge to approx-top-3 (redundant per cg)
    float4 eA = best12[p];          float2 eA3 = best3[p];
    float4 eB = best12[N_ + p];     float2 eB3 = best3[N_ + p];
    float s1 = eA.x, s2 = eA.z, s3 = eA3.x;
    unsigned i1 = __float_as_uint(eA.y), i2 = __float_as_uint(eA.w), i3 = __float_as_uint(eA3.y);
    insert3(s1, i1, s2, i2, s3, i3, eB.x,  __float_as_uint(eB.y));
    insert3(s1, i1, s2, i2, s3, i3, eB.z,  __float_as_uint(eB.w));
    insert3(s1, i1, s2, i2, s3, i3, eB3.x, __float_as_uint(eB3.y));
    unsigned ci[3] = { i1, i2, i3 };

    float rn = rnorm[p];
    const float* kp0 = keys + (size_t)ci[0] * D_;
    const float* kp1 = keys + (size_t)ci[1] * D_;
    const float* kp2 = keys + (size_t)ci[2] * D_;
    float d0 = 0.f, d1 = 0.f, d2 = 0.f, h0 = 0.f, h1 = 0.f, h2 = 0.f;
    for (int c = cg * 128; c < cg * 128 + 128; c += 4) {
        float qv[4];
#pragma unroll
        for (int j = 0; j < 4; ++j) qv[j] = qb[(size_t)(c + j) * HW_] * rn;  // coalesced
        float4 k0 = *(const float4*)(kp0 + c);
        float4 k1 = *(const float4*)(kp1 + c);
        float4 k2 = *(const float4*)(kp2 + c);
        d0 += qv[0] * k0.x + qv[1] * k0.y + qv[2] * k0.z + qv[3] * k0.w;
        d1 += qv[0] * k1.x + qv[1] * k1.y + qv[2] * k1.z + qv[3] * k1.w;
        d2 += qv[0] * k2.x + qv[1] * k2.y + qv[2] * k2.z + qv[3] * k2.w;
#pragma unroll
        for (int j = 0; j < 4; ++j) {
            float kj0 = ((const float*)&k0)[j], kj1 = ((const float*)&k1)[j], kj2 = ((const float*)&k2)[j];
            float a = qv[j] - kj0, b = qv[j] - kj1, cc = qv[j] - kj2;
            float a2 = a * a, b2 = b * b, c2 = cc * cc;
            h0 += a2 * a2; h1 += b2 * b2; h2 += c2 * c2;
        }
    }
    pA[pl][cg] = make_float4(d0, d1, d2, h0);
    pB[pl][cg] = make_float4(h1, h2, 0.f, 0.f);
    __syncthreads();
    if (t < 64) {                                // cg==0 thread for pixel t holds ci[]
        float D0 = 0.f, D1 = 0.f, D2 = 0.f, H0 = 0.f, H1 = 0.f, H2 = 0.f;
#pragma unroll
        for (int g = 0; g < 4; ++g) {
            float4 a = pA[t][g], b = pB[t][g];
            D0 += a.x; D1 += a.y; D2 += a.z; H0 += a.w; H1 += b.x; H2 += b.y;
        }
        float sA = kn[ci[0]] - 2.0f * D0;
        float sB = kn[ci[1]] - 2.0f * D1;
        float sC = kn[ci[2]] - 2.0f * D2;
        // exact argmin among candidates; tie -> smaller index
        float bs = sA; unsigned bi = ci[0]; float bh = H0;
        if (sB < bs || (sB == bs && ci[1] < bi)) { bs = sB; bi = ci[1]; bh = H1; }
        if (sC < bs || (sC == bs && ci[2] < bi)) { bs = sC; bi = ci[2]; bh = H2; }
        out[p0 + t] = bh;
    }
}

extern "C" void kernel_launch(void* const* d_in, const int* in_sizes, int n_in,
                              void* d_out, int out_size, void* d_ws, size_t ws_size,
                              hipStream_t stream) {
    const float* query = (const float*)d_in[0];   // (8,512,64,64) f32
    const float* keys  = (const float*)d_in[1];   // (2000,512) f32
    float* out = (float*)d_out;                   // 32768 f32

    // workspace layout (~20 MB):
    char* ws = (char*)d_ws;
    unsigned char* qsw8 = (unsigned char*)ws;                        // N*D fp8   = 16.8 MB
    unsigned char* ksw8 = qsw8 + (size_t)N_ * D_;                    // MP*D fp8  = 1 MB
    float*  rnorm  = (float*)(ksw8 + (size_t)MP_ * D_);
    float*  kn     = rnorm + N_;
    float4* best12 = (float4*)(kn + MP_);                            // 2*N float4 = 1 MB
    float2* best3  = (float2*)(best12 + 2 * (size_t)N_);             // 2*N float2 = 0.5 MB

    k_keys<<<MP_ / 4,           256, 0, stream>>>(keys, kn, ksw8);
    k_prep<<<N_ / 64,           256, 0, stream>>>(query, rnorm, qsw8);
    k_mfma<<<dim3(N_ / 128, 2), 256, 0, stream>>>(qsw8, ksw8, kn, rnorm, best12, best3);
    k_heat<<<N_ / 64,           256, 0, stream>>>(query, keys, kn, rnorm, best12, best3, out);
}

// Round 2
// 180.058 us; speedup vs baseline: 2.4835x; 2.4835x over previous
//
#include <hip/hip_runtime.h>
#include <float.h>
#include <math.h>

// Problem constants: query (8,512,64,64) f32, keys (2000,512) f32
constexpr int D_  = 512;
constexpr int HW_ = 4096;           // 64*64
constexpr int N_  = 32768;          // B*HW
constexpr int M_  = 2000;
constexpr int MP_ = 2048;           // padded key count

// fp8 stores RAW q (no pre-normalization, no scale): e4m3 relative error is
// scale-invariant; rnorm is folded into the score at fold time (fr[r] = -2*rnorm).
// Numerics of this scheme were harness-verified in R1 (passed, absmax 8.0).

typedef int          i32x8  __attribute__((ext_vector_type(8)));
typedef float        f32x16 __attribute__((ext_vector_type(16)));
typedef unsigned int uu32x4 __attribute__((ext_vector_type(4)));
typedef unsigned int uu32x2 __attribute__((ext_vector_type(2)));

__device__ inline unsigned umn(unsigned a, unsigned b) { return a < b ? a : b; }
__device__ inline unsigned umx(unsigned a, unsigned b) { return a > b ? a : b; }

// single-instruction unsigned median-of-3 (VOP3, gfx9+)
__device__ inline unsigned med3u(unsigned a, unsigned b, unsigned c) {
    unsigned d;
    asm("v_med3_u32 %0, %1, %2, %3" : "=v"(d) : "v"(a), "v"(b), "v"(c));
    return d;
}

// pack 4 floats -> 4 OCP e4m3 bytes (v_cvt_pk_fp8_f32; OCP format on gfx950)
__device__ inline unsigned pk4f8(float a, float b, float c, float d) {
    int v = 0;
    v = __builtin_amdgcn_cvt_pk_fp8_f32(a, b, v, false);   // bytes 0-1
    v = __builtin_amdgcn_cvt_pk_fp8_f32(c, d, v, true);    // bytes 2-3
    return (unsigned)v;
}

// ---------------- kernel 1: SINGLE-PASS rnorm + fp8 A-fragment swizzle ----------------
// qsw8 holds raw q in e4m3, 32x32x64-A-fragment order:
// frag (pb32, kc64): lane L byte j  <->  A[m = pb*32 + (L&31)][k = kc*64 + (L>>5)*32 + j]
// Sum-of-squares accumulates in registers during the same tile loads that feed the
// fp8 emit -> query is read from HBM exactly once (was twice in R0).
__global__ __launch_bounds__(256) void k_prep(const float* __restrict__ q,
                                              float* __restrict__ rnorm,
                                              unsigned char* __restrict__ qsw8) {
    __shared__ float  tile[64][65];
    __shared__ float4 part2[16][17];
    int t = threadIdx.x;
    int p0 = blockIdx.x * 64;                    // 64 | 4096 -> single batch per block
    const float* base = q + (size_t)(p0 / HW_) * (D_ * HW_) + (p0 % HW_);
    int pb0 = blockIdx.x * 2;                    // pb32 base (2 per block)

    float s0 = 0.f, s1 = 0.f, s2 = 0.f, s3 = 0.f;  // sumsq partials for px quad (t&15)*4
    for (int ct = 0; ct < 8; ++ct) {             // kc64 = ct
        if (ct) __syncthreads();                 // prev emit done before tile overwrite
#pragma unroll
        for (int i = 0; i < 4; ++i) {
            int sl = t + 256 * i;                // 1024 float4 slots: 64 ch-rows x 16
            int row = sl >> 4, p4 = (sl & 15) * 4;
            float4 v = *(const float4*)(base + (size_t)(ct * 64 + row) * HW_ + p4);
            s0 += v.x * v.x; s1 += v.y * v.y; s2 += v.z * v.z; s3 += v.w * v.w;
            tile[row][p4 + 0] = v.x; tile[row][p4 + 1] = v.y;
            tile[row][p4 + 2] = v.z; tile[row][p4 + 3] = v.w;
        }
        __syncthreads();
        {
            // 256 slots: 2 pb-frags x 64 lanes x 2 16B-halves
            int pbi = t >> 7, L = (t >> 1) & 63, hf = t & 1;
            int plx = pbi * 32 + (L & 31);
            int cl  = (L >> 5) * 32 + hf * 16;
            unsigned d[4];
#pragma unroll
            for (int w4 = 0; w4 < 4; ++w4)
                d[w4] = pk4f8(tile[cl + w4 * 4 + 0][plx],
                              tile[cl + w4 * 4 + 1][plx],
                              tile[cl + w4 * 4 + 2][plx],
                              tile[cl + w4 * 4 + 3][plx]);
            *(uu32x4*)(qsw8 + (((size_t)(pb0 + pbi) * 8 + ct) * 64 + L) * 32 + hf * 16)
                = (uu32x4){d[0], d[1], d[2], d[3]};
        }
    }
    // reduce sumsq: thread t held px quad (t&15)*4 over ch rows {t>>4 + 16i + 64ct}
    part2[t & 15][t >> 4] = make_float4(s0, s1, s2, s3);
    __syncthreads();
    if (t < 64) {
        float ss = 0.f;
#pragma unroll
        for (int g = 0; g < 16; ++g)
            ss += ((const float*)&part2[t >> 2][g])[t & 3];
        rnorm[p0 + t] = 1.0f / fmaxf(sqrtf(ss), 1e-12f);   // matches F.normalize eps
    }
}

// ---------------- kernel 2: fused |k|^2 + fp8 B-fragment swizzle ----------------
// frag (nb32, kc64): lane L byte j <-> B[k = kc*64 + (L>>5)*32 + j][n = nb*32 + (L&31)]
__global__ __launch_bounds__(256) void k_keys(const float* __restrict__ keys,
                                              float* __restrict__ kn,
                                              unsigned char* __restrict__ ksw8) {
    int wave = threadIdx.x >> 6;
    int lane = threadIdx.x & 63;
    int m = blockIdx.x * 4 + wave;               // grid 512 -> m in [0,2048)
    int kc = lane >> 3, sub = lane & 7;
    int kh = sub >> 2, bg = sub & 3;
    int c = kc * 64 + kh * 32 + bg * 8;          // 8 channels per lane, covers all 512
    float4 v0 = make_float4(0.f, 0.f, 0.f, 0.f);
    float4 v1 = make_float4(0.f, 0.f, 0.f, 0.f);
    if (m < M_) {
        const float* row = keys + (size_t)m * D_ + c;
        v0 = *(const float4*)(row);
        v1 = *(const float4*)(row + 4);
    }
    float s = v0.x * v0.x + v0.y * v0.y + v0.z * v0.z + v0.w * v0.w
            + v1.x * v1.x + v1.y * v1.y + v1.z * v1.z + v1.w * v1.w;
    for (int off = 32; off; off >>= 1) s += __shfl_down(s, off, 64);
    if (lane == 0) kn[m] = (m < M_) ? s : FLT_MAX;
    unsigned d0 = pk4f8(v0.x, v0.y, v0.z, v0.w);
    unsigned d1 = pk4f8(v1.x, v1.y, v1.z, v1.w);
    *(uu32x2*)(ksw8 + (((size_t)(m >> 5) * 8 + kc) * 64 + kh * 32 + (m & 31)) * 32 + bg * 8)
        = (uu32x2){d0, d1};
}

// insert (t,j) into sorted top-3 (s1<=s2<=s3) with index tie-break
__device__ inline void insert3(float& s1, unsigned& i1, float& s2, unsigned& i2,
                               float& s3, unsigned& i3, float t, unsigned j) {
    if (t < s1 || (t == s1 && j < i1))      { s3 = s2; i3 = i2; s2 = s1; i2 = i1; s1 = t; i1 = j; }
    else if (t < s2 || (t == s2 && j < i2)) { s3 = s2; i3 = i2; s2 = t; i2 = j; }
    else if (t < s3 || (t == s3 && j < i3)) { s3 = t; i3 = j; }
}

// ---------------- kernel 3: fp8 MX MFMA score GEMM (32x32x64, scales = 1.0) ----------------
// R2: PROVEN R0 skeleton restored (accumulate in place over kc, fold once per chunk,
// explicit reset AFTER the full fold, depth-1 cur/nxt prefetch, no fresh-def SSA games
// -- R1's fresh-def interleave needed 2 live acc copies -> scratch spill, 895 MB writes).
// Kept from R1 (numerics verified): raw-q fp8, per-pixel fr[] fold factor, med3 3-op
// insert (was 5 ops). Score s = kn - 2*rnorm[pix]*acc > 0 -> float bits compare as
// unsigned. 10-bit id in low mantissa (~0.06 trunc; fp8 noise ~0.05 -- both absorbed
// by the top-3 + exact-fp32 rescue).
__global__ __launch_bounds__(256) void k_mfma(const unsigned char* __restrict__ qsw8,
                                              const unsigned char* __restrict__ ksw8,
                                              const float* __restrict__ kn,
                                              const float* __restrict__ rnorm,
                                              float4* __restrict__ best12,
                                              float2* __restrict__ best3) {
    __shared__ float kns[1024];
    __shared__ float rns[128];
    int t = threadIdx.x;
    int lane = t & 63;
    int wr = __builtin_amdgcn_readfirstlane(t >> 6);   // pixel-row group 0..3
    int colk = lane & 31, h = lane >> 5;
    int p0 = blockIdx.x * 128;
    int yb = blockIdx.y;                               // key half: yb*1024
#pragma unroll
    for (int i = 0; i < 4; ++i) kns[t + 256 * i] = kn[yb * 1024 + t + 256 * i];
    if (t < 128) rns[t] = rnorm[p0 + t];
    __syncthreads();

    // per-lane fold factors: fr[r] = -2*rnorm[pixel(r,h)] (32x32 C/D row map)
    float fr[16];
#pragma unroll
    for (int r = 0; r < 16; ++r)
        fr[r] = -2.0f * rns[wr * 32 + (r & 3) + 8 * (r >> 2) + 4 * h];

    // lane-resolved fragment bases (bytes). A(kc) = aq + kc*2048;
    // B(ni,ch,kc) = bk + ((ch*4+ni)*8 + kc)*2048
    const unsigned char* aq = qsw8 + ((size_t)(blockIdx.x * 4 + wr) * 8) * 2048 + lane * 32;
    const unsigned char* bk = ksw8 + ((size_t)(yb * 32) * 8) * 2048 + lane * 32;

    unsigned pk1[16], pk2[16], pk3[16];
#pragma unroll
    for (int i = 0; i < 16; ++i) { pk1[i] = 0xFFFFFFFFu; pk2[i] = 0xFFFFFFFFu; pk3[i] = 0xFFFFFFFFu; }

    f32x16 acc[4];
#pragma unroll
    for (int ni = 0; ni < 4; ++ni)
#pragma unroll
        for (int r = 0; r < 16; ++r) acc[ni][r] = 0.f;

    int scl = 0x7F7F7F7F;                        // e8m0 = 127 -> x1.0 in every byte/lane

    i32x8 curA, nxtA, curB[4], nxtB[4];
    curA = *(const i32x8*)(aq);
#pragma unroll
    for (int ni = 0; ni < 4; ++ni) curB[ni] = *(const i32x8*)(bk + (size_t)(ni * 8) * 2048);

#pragma unroll 2
    for (int g = 0; g < 64; ++g) {
        if (g < 63) {                            // prefetch step g+1
            int g1 = g + 1;
            int kc = g1 & 7, ch = g1 >> 3;
            nxtA = *(const i32x8*)(aq + (size_t)kc * 2048);
#pragma unroll
            for (int ni = 0; ni < 4; ++ni)
                nxtB[ni] = *(const i32x8*)(bk + (size_t)((ch * 4 + ni) * 8 + kc) * 2048);
        }
#pragma unroll
        for (int ni = 0; ni < 4; ++ni)
            acc[ni] = __builtin_amdgcn_mfma_scale_f32_32x32x64_f8f6f4(
                curA, curB[ni], acc[ni], 0, 0, 0, scl, 0, scl);

        if ((g & 7) == 7) {                      // chunk complete: fold ALL scores...
            int ch = g >> 3;
            float kc4[4];
#pragma unroll
            for (int ni = 0; ni < 4; ++ni) kc4[ni] = kns[ch * 128 + ni * 32 + colk];
#pragma unroll
            for (int ni = 0; ni < 4; ++ni) {
                unsigned idbase = ((unsigned)(ch * 4 + ni) << 5) | (unsigned)colk;
#pragma unroll
                for (int r = 0; r < 16; ++r) {
                    float sc = fmaf(fr[r], acc[ni][r], kc4[ni]);
                    unsigned p = (__float_as_uint(sc) & ~1023u) | idbase;   // v_and_or_b32
                    // med3 insert into sorted top-3: 3 ops (was 5 min/max)
                    unsigned n2 = med3u(pk1[r], pk2[r], p);
                    unsigned n3 = med3u(pk2[r], pk3[r], p);
                    pk1[r] = umn(pk1[r], p);
                    pk2[r] = n2;
                    pk3[r] = n3;
                }
            }
            // ...then reset accumulators (AFTER the full fold — R6 lesson)
#pragma unroll
            for (int ni = 0; ni < 4; ++ni)
#pragma unroll
                for (int r = 0; r < 16; ++r) acc[ni][r] = 0.f;
        }
#pragma unroll
        for (int ni = 0; ni < 4; ++ni) curB[ni] = nxtB[ni];
        curA = nxtA;
    }

    // ---- epilogue: packed-list butterfly over the 32 colk lanes; writers store top-3 ----
#pragma unroll
    for (int r = 0; r < 16; ++r) {
        unsigned a1 = pk1[r], a2 = pk2[r], a3 = pk3[r];
#pragma unroll
        for (int mask = 1; mask < 32; mask <<= 1) {
            unsigned b1 = (unsigned)__shfl_xor((int)a1, mask, 64);
            unsigned b2 = (unsigned)__shfl_xor((int)a2, mask, 64);
            unsigned b3 = (unsigned)__shfl_xor((int)a3, mask, 64);
            unsigned x1 = umn(a1, b1), y1 = umx(a1, b1);
            unsigned x2 = umn(a2, b2);
            unsigned z  = umn(a3, b3);
            a1 = x1;
            a2 = umn(y1, x2);
            a3 = umn(umx(y1, x2), z);
        }
        if (colk == 0) {
            int pix = wr * 32 + (r & 3) + 8 * (r >> 2) + 4 * h;   // 32x32 C/D row map
            // unpack: score (trunc) + global key index
            unsigned l1 = a1 & 1023u, l2 = a2 & 1023u, l3 = a3 & 1023u;
            unsigned m1 = (unsigned)(yb * 1024) + (l1 >> 7) * 128 + ((l1 >> 5) & 3) * 32 + (l1 & 31);
            unsigned m2 = (unsigned)(yb * 1024) + (l2 >> 7) * 128 + ((l2 >> 5) & 3) * 32 + (l2 & 31);
            unsigned m3 = (unsigned)(yb * 1024) + (l3 >> 7) * 128 + ((l3 >> 5) & 3) * 32 + (l3 & 31);
            size_t o = (size_t)yb * N_ + p0 + pix;
            best12[o] = make_float4(__uint_as_float(a1 & ~1023u), __uint_as_float(m1),
                                    __uint_as_float(a2 & ~1023u), __uint_as_float(m2));
            best3[o]  = make_float2(__uint_as_float(a3 & ~1023u), __uint_as_float(m3));
        }
    }
}

// ---------------- kernel 4: merge 6 cands -> approx-top-3, exact fp32 rescue + heatmap ----------------
// Block = 64 pixels x 4 c-groups (256 thr). Reads fp32 q (NOT fp8): rescue must be exact.
__global__ __launch_bounds__(256) void k_heat(
    const float* __restrict__ q, const float* __restrict__ keys,
    const float* __restrict__ kn, const float* __restrict__ rnorm,
    const float4* __restrict__ best12, const float2* __restrict__ best3,
    float* __restrict__ out)
{
    __shared__ float4 pA[64][5];                 // (d0,d1,d2,h0) x 4 cg (+1 pad)
    __shared__ float4 pB[64][5];                 // (h1,h2,-,-)
    int t = threadIdx.x;
    int pl = t & 63, cg = t >> 6;
    int p0 = blockIdx.x * 64;
    int p = p0 + pl;
    const float* qb = q + (size_t)(p / HW_) * (D_ * HW_) + (p % HW_);

    // gather the 2 halves' top-3 lists, merge to approx-top-3 (redundant per cg)
    float4 eA = best12[p];          float2 eA3 = best3[p];
    float4 eB = best12[N_ + p];     float2 eB3 = best3[N_ + p];
    float s1 = eA.x, s2 = eA.z, s3 = eA3.x;
    unsigned i1 = __float_as_uint(eA.y), i2 = __float_as_uint(eA.w), i3 = __float_as_uint(eA3.y);
    insert3(s1, i1, s2, i2, s3, i3, eB.x,  __float_as_uint(eB.y));
    insert3(s1, i1, s2, i2, s3, i3, eB.z,  __float_as_uint(eB.w));
    insert3(s1, i1, s2, i2, s3, i3, eB3.x, __float_as_uint(eB3.y));
    unsigned ci[3] = { i1, i2, i3 };

    float rn = rnorm[p];
    const float* kp0 = keys + (size_t)ci[0] * D_;
    const float* kp1 = keys + (size_t)ci[1] * D_;
    const float* kp2 = keys + (size_t)ci[2] * D_;
    float d0 = 0.f, d1 = 0.f, d2 = 0.f, h0 = 0.f, h1 = 0.f, h2 = 0.f;
    for (int c = cg * 128; c < cg * 128 + 128; c += 4) {
        float qv[4];
#pragma unroll
        for (int j = 0; j < 4; ++j) qv[j] = qb[(size_t)(c + j) * HW_] * rn;  // coalesced
        float4 k0 = *(const float4*)(kp0 + c);
        float4 k1 = *(const float4*)(kp1 + c);
        float4 k2 = *(const float4*)(kp2 + c);
        d0 += qv[0] * k0.x + qv[1] * k0.y + qv[2] * k0.z + qv[3] * k0.w;
        d1 += qv[0] * k1.x + qv[1] * k1.y + qv[2] * k1.z + qv[3] * k1.w;
        d2 += qv[0] * k2.x + qv[1] * k2.y + qv[2] * k2.z + qv[3] * k2.w;
#pragma unroll
        for (int j = 0; j < 4; ++j) {
            float kj0 = ((const float*)&k0)[j], kj1 = ((const float*)&k1)[j], kj2 = ((const float*)&k2)[j];
            float a = qv[j] - kj0, b = qv[j] - kj1, cc = qv[j] - kj2;
            float a2 = a * a, b2 = b * b, c2 = cc * cc;
            h0 += a2 * a2; h1 += b2 * b2; h2 += c2 * c2;
        }
    }
    pA[pl][cg] = make_float4(d0, d1, d2, h0);
    pB[pl][cg] = make_float4(h1, h2, 0.f, 0.f);
    __syncthreads();
    if (t < 64) {                                // cg==0 thread for pixel t holds ci[]
        float D0 = 0.f, D1 = 0.f, D2 = 0.f, H0 = 0.f, H1 = 0.f, H2 = 0.f;
#pragma unroll
        for (int g = 0; g < 4; ++g) {
            float4 a = pA[t][g], b = pB[t][g];
            D0 += a.x; D1 += a.y; D2 += a.z; H0 += a.w; H1 += b.x; H2 += b.y;
        }
        float sA = kn[ci[0]] - 2.0f * D0;
        float sB = kn[ci[1]] - 2.0f * D1;
        float sC = kn[ci[2]] - 2.0f * D2;
        // exact argmin among candidates; tie -> smaller index
        float bs = sA; unsigned bi = ci[0]; float bh = H0;
        if (sB < bs || (sB == bs && ci[1] < bi)) { bs = sB; bi = ci[1]; bh = H1; }
        if (sC < bs || (sC == bs && ci[2] < bi)) { bs = sC; bi = ci[2]; bh = H2; }
        out[p0 + t] = bh;
    }
}

extern "C" void kernel_launch(void* const* d_in, const int* in_sizes, int n_in,
                              void* d_out, int out_size, void* d_ws, size_t ws_size,
                              hipStream_t stream) {
    const float* query = (const float*)d_in[0];   // (8,512,64,64) f32
    const float* keys  = (const float*)d_in[1];   // (2000,512) f32
    float* out = (float*)d_out;                   // 32768 f32

    // workspace layout (~20 MB):
    char* ws = (char*)d_ws;
    unsigned char* qsw8 = (unsigned char*)ws;                        // N*D fp8   = 16.8 MB
    unsigned char* ksw8 = qsw8 + (size_t)N_ * D_;                    // MP*D fp8  = 1 MB
    float*  rnorm  = (float*)(ksw8 + (size_t)MP_ * D_);
    float*  kn     = rnorm + N_;
    float4* best12 = (float4*)(kn + MP_);                            // 2*N float4 = 1 MB
    float2* best3  = (float2*)(best12 + 2 * (size_t)N_);             // 2*N float2 = 0.5 MB

    k_keys<<<MP_ / 4,           256, 0, stream>>>(keys, kn, ksw8);
    k_prep<<<N_ / 64,           256, 0, stream>>>(query, rnorm, qsw8);
    k_mfma<<<dim3(N_ / 128, 2), 256, 0, stream>>>(qsw8, ksw8, kn, rnorm, best12, best3);
    k_heat<<<N_ / 64,           256, 0, stream>>>(query, keys, kn, rnorm, best12, best3, out);
}

// Round 3
// 157.034 us; speedup vs baseline: 2.8477x; 1.1466x over previous
//
#include <hip/hip_runtime.h>
#include <float.h>
#include <math.h>

// Problem constants: query (8,512,64,64) f32, keys (2000,512) f32
constexpr int D_  = 512;
constexpr int HW_ = 4096;           // 64*64
constexpr int N_  = 32768;          // B*HW
constexpr int M_  = 2000;
constexpr int MP_ = 2048;           // padded key count

// fp8 stores RAW q; rnorm folded into the score at fold time (fr[r] = -2*rnorm).
// Numerics harness-verified in R1/R2 (passed, absmax 8.0).

typedef int          i32x8  __attribute__((ext_vector_type(8)));
typedef float        f32x16 __attribute__((ext_vector_type(16)));
typedef unsigned int uu32x4 __attribute__((ext_vector_type(4)));
typedef unsigned int uu32x2 __attribute__((ext_vector_type(2)));

__device__ inline unsigned umn(unsigned a, unsigned b) { return a < b ? a : b; }
__device__ inline unsigned umx(unsigned a, unsigned b) { return a > b ? a : b; }

// single-instruction unsigned median-of-3 (VOP3, gfx9+)
__device__ inline unsigned med3u(unsigned a, unsigned b, unsigned c) {
    unsigned d;
    asm("v_med3_u32 %0, %1, %2, %3" : "=v"(d) : "v"(a), "v"(b), "v"(c));
    return d;
}

// pack 4 floats -> 4 OCP e4m3 bytes (v_cvt_pk_fp8_f32; OCP format on gfx950)
__device__ inline unsigned pk4f8(float a, float b, float c, float d) {
    int v = 0;
    v = __builtin_amdgcn_cvt_pk_fp8_f32(a, b, v, false);   // bytes 0-1
    v = __builtin_amdgcn_cvt_pk_fp8_f32(c, d, v, true);    // bytes 2-3
    return (unsigned)v;
}

// ---------------- kernel 1: SINGLE-PASS rnorm + fp8 A-fragment swizzle ----------------
// qsw8 holds raw q in e4m3, 32x32x64-A-fragment order:
// frag (pb32, kc64): lane L byte j  <->  A[m = pb*32 + (L&31)][k = kc*64 + (L>>5)*32 + j]
__global__ __launch_bounds__(256) void k_prep(const float* __restrict__ q,
                                              float* __restrict__ rnorm,
                                              unsigned char* __restrict__ qsw8) {
    __shared__ float  tile[64][65];
    __shared__ float4 part2[16][17];
    int t = threadIdx.x;
    int p0 = blockIdx.x * 64;                    // 64 | 4096 -> single batch per block
    const float* base = q + (size_t)(p0 / HW_) * (D_ * HW_) + (p0 % HW_);
    int pb0 = blockIdx.x * 2;                    // pb32 base (2 per block)

    float s0 = 0.f, s1 = 0.f, s2 = 0.f, s3 = 0.f;  // sumsq partials for px quad (t&15)*4
    for (int ct = 0; ct < 8; ++ct) {             // kc64 = ct
        if (ct) __syncthreads();                 // prev emit done before tile overwrite
#pragma unroll
        for (int i = 0; i < 4; ++i) {
            int sl = t + 256 * i;                // 1024 float4 slots: 64 ch-rows x 16
            int row = sl >> 4, p4 = (sl & 15) * 4;
            float4 v = *(const float4*)(base + (size_t)(ct * 64 + row) * HW_ + p4);
            s0 += v.x * v.x; s1 += v.y * v.y; s2 += v.z * v.z; s3 += v.w * v.w;
            tile[row][p4 + 0] = v.x; tile[row][p4 + 1] = v.y;
            tile[row][p4 + 2] = v.z; tile[row][p4 + 3] = v.w;
        }
        __syncthreads();
        {
            // 256 slots: 2 pb-frags x 64 lanes x 2 16B-halves
            int pbi = t >> 7, L = (t >> 1) & 63, hf = t & 1;
            int plx = pbi * 32 + (L & 31);
            int cl  = (L >> 5) * 32 + hf * 16;
            unsigned d[4];
#pragma unroll
            for (int w4 = 0; w4 < 4; ++w4)
                d[w4] = pk4f8(tile[cl + w4 * 4 + 0][plx],
                              tile[cl + w4 * 4 + 1][plx],
                              tile[cl + w4 * 4 + 2][plx],
                              tile[cl + w4 * 4 + 3][plx]);
            *(uu32x4*)(qsw8 + (((size_t)(pb0 + pbi) * 8 + ct) * 64 + L) * 32 + hf * 16)
                = (uu32x4){d[0], d[1], d[2], d[3]};
        }
    }
    // reduce sumsq: thread t held px quad (t&15)*4 over ch rows {t>>4 + 16i + 64ct}
    part2[t & 15][t >> 4] = make_float4(s0, s1, s2, s3);
    __syncthreads();
    if (t < 64) {
        float ss = 0.f;
#pragma unroll
        for (int g = 0; g < 16; ++g)
            ss += ((const float*)&part2[t >> 2][g])[t & 3];
        rnorm[p0 + t] = 1.0f / fmaxf(sqrtf(ss), 1e-12f);   // matches F.normalize eps
    }
}

// ---------------- kernel 2: fused |k|^2 + fp8 B-fragment swizzle ----------------
// frag (nb32, kc64): lane L byte j <-> B[k = kc*64 + (L>>5)*32 + j][n = nb*32 + (L&31)]
__global__ __launch_bounds__(256) void k_keys(const float* __restrict__ keys,
                                              float* __restrict__ kn,
                                              unsigned char* __restrict__ ksw8) {
    int wave = threadIdx.x >> 6;
    int lane = threadIdx.x & 63;
    int m = blockIdx.x * 4 + wave;               // grid 512 -> m in [0,2048)
    int kc = lane >> 3, sub = lane & 7;
    int kh = sub >> 2, bg = sub & 3;
    int c = kc * 64 + kh * 32 + bg * 8;          // 8 channels per lane, covers all 512
    float4 v0 = make_float4(0.f, 0.f, 0.f, 0.f);
    float4 v1 = make_float4(0.f, 0.f, 0.f, 0.f);
    if (m < M_) {
        const float* row = keys + (size_t)m * D_ + c;
        v0 = *(const float4*)(row);
        v1 = *(const float4*)(row + 4);
    }
    float s = v0.x * v0.x + v0.y * v0.y + v0.z * v0.z + v0.w * v0.w
            + v1.x * v1.x + v1.y * v1.y + v1.z * v1.z + v1.w * v1.w;
    for (int off = 32; off; off >>= 1) s += __shfl_down(s, off, 64);
    if (lane == 0) kn[m] = (m < M_) ? s : FLT_MAX;
    unsigned d0 = pk4f8(v0.x, v0.y, v0.z, v0.w);
    unsigned d1 = pk4f8(v1.x, v1.y, v1.z, v1.w);
    *(uu32x2*)(ksw8 + (((size_t)(m >> 5) * 8 + kc) * 64 + kh * 32 + (m & 31)) * 32 + bg * 8)
        = (uu32x2){d0, d1};
}

// insert (t,j) into sorted top-3 (s1<=s2<=s3) with index tie-break
__device__ inline void insert3(float& s1, unsigned& i1, float& s2, unsigned& i2,
                               float& s3, unsigned& i3, float t, unsigned j) {
    if (t < s1 || (t == s1 && j < i1))      { s3 = s2; i3 = i2; s2 = s1; i2 = i1; s1 = t; i1 = j; }
    else if (t < s2 || (t == s2 && j < i2)) { s3 = s2; i3 = i2; s2 = t; i2 = j; }
    else if (t < s3 || (t == s3 && j < i3)) { s3 = t; i3 = j; }
}

// ---------------- kernel 3: fp8 MX MFMA score GEMM, LDS-staged B ----------------
// R3: L2-traffic restructure. 8-wave (512-thr) blocks, 256 px each, grid (128,2).
// B chunk (64 keys = 32 KB, CONTIGUOUS in ksw8) double-buffered in LDS: staged once
// per block (reg-staged: global->reg at chunk top, ds_write after fold -> HBM/L2
// latency hides under the chunk's 16 MFMAs; ONE barrier per chunk). All 8 A-frags
// for the wave's 32-px group preloaded into 64 VGPRs (reused by all 16 chunks) ->
// zero A loads in the main loop. L2 traffic ~1.26 GB -> ~170 MB. ds_read pattern is
// lane-linear 32B stride = contiguous 2KB/wave = conflict-free.
// 10-bit id = local key index within the yb half (decode m = yb*1024 + id).
__global__ __launch_bounds__(512, 2) void k_mfma(const unsigned char* __restrict__ qsw8,
                                                 const unsigned char* __restrict__ ksw8,
                                                 const float* __restrict__ kn,
                                                 const float* __restrict__ rnorm,
                                                 float4* __restrict__ best12,
                                                 float2* __restrict__ best3) {
    __shared__ uu32x4 bbuf[2][2048];             // 2 x 32 KiB chunk double buffer
    int t = threadIdx.x;
    int lane = t & 63;
    int w = __builtin_amdgcn_readfirstlane(t >> 6);    // wave 0..7 -> px rows w*32..+32
    int colk = lane & 31, h = lane >> 5;
    int p0 = blockIdx.x * 256;
    int yb = blockIdx.y;                               // key half: yb*1024

    // per-lane fold factors fr[r] = -2*rnorm[pixel(r,h)] (32x32 C/D row map)
    float fr[16];
#pragma unroll
    for (int r = 0; r < 16; ++r)
        fr[r] = -2.0f * rnorm[p0 + w * 32 + (r & 3) + 8 * (r >> 2) + 4 * h];

    // preload ALL 8 A-frags of this wave's px group (16 KB -> 64 VGPR, reused 16x)
    const unsigned char* aq = qsw8 + ((size_t)(blockIdx.x * 8 + w) * 8) * 2048 + lane * 32;
    i32x8 a0 = *(const i32x8*)(aq);
    i32x8 a1 = *(const i32x8*)(aq + 2048);
    i32x8 a2 = *(const i32x8*)(aq + 4096);
    i32x8 a3 = *(const i32x8*)(aq + 6144);
    i32x8 a4 = *(const i32x8*)(aq + 8192);
    i32x8 a5 = *(const i32x8*)(aq + 10240);
    i32x8 a6 = *(const i32x8*)(aq + 12288);
    i32x8 a7 = *(const i32x8*)(aq + 14336);

    const unsigned char* bsrc = ksw8 + ((size_t)yb * 32 * 8) * 2048;   // half base

    // stage chunk 0
    {
        uu32x4 s0[4];
#pragma unroll
        for (int r = 0; r < 4; ++r)
            s0[r] = *(const uu32x4*)(bsrc + ((size_t)(r * 512 + t)) * 16);
#pragma unroll
        for (int r = 0; r < 4; ++r) bbuf[0][r * 512 + t] = s0[r];
    }
    __syncthreads();

    unsigned pk1[16], pk2[16], pk3[16];
#pragma unroll
    for (int i = 0; i < 16; ++i) { pk1[i] = 0xFFFFFFFFu; pk2[i] = 0xFFFFFFFFu; pk3[i] = 0xFFFFFFFFu; }

    int scl = 0x7F7F7F7F;                        // e8m0 = 127 -> x1.0 in every byte/lane

#pragma unroll 1
    for (int c = 0; c < 16; ++c) {               // 16 chunks x 64 keys
        int cb = c & 1;
        // issue next-chunk stage loads early (consumed by ds_write AFTER the fold)
        uu32x4 stg[4];
        if (c < 15) {
            const unsigned char* s = bsrc + (size_t)(c + 1) * 32768;
#pragma unroll
            for (int r = 0; r < 4; ++r)
                stg[r] = *(const uu32x4*)(s + ((size_t)(r * 512 + t)) * 16);
        }
        float kn0 = kn[yb * 1024 + c * 64 + colk];
        float kn1 = kn[yb * 1024 + c * 64 + 32 + colk];

        const unsigned char* bb = (const unsigned char*)(&bbuf[cb][0]) + lane * 32;
        f32x16 acc0, acc1;
#pragma unroll
        for (int r = 0; r < 16; ++r) { acc0[r] = 0.f; acc1[r] = 0.f; }

#pragma unroll
        for (int kc = 0; kc < 8; ++kc) {
            i32x8 b0 = *(const i32x8*)(bb + (size_t)kc * 2048);          // ni=0
            i32x8 b1 = *(const i32x8*)(bb + (size_t)(8 + kc) * 2048);    // ni=1
            i32x8 av = (kc == 0) ? a0 : (kc == 1) ? a1 : (kc == 2) ? a2 : (kc == 3) ? a3
                     : (kc == 4) ? a4 : (kc == 5) ? a5 : (kc == 6) ? a6 : a7;
            acc0 = __builtin_amdgcn_mfma_scale_f32_32x32x64_f8f6f4(
                av, b0, acc0, 0, 0, 0, scl, 0, scl);
            acc1 = __builtin_amdgcn_mfma_scale_f32_32x32x64_f8f6f4(
                av, b1, acc1, 0, 0, 0, scl, 0, scl);
        }

        // fold this chunk's 32 scores (2 key columns x 16 rows)
        unsigned id0 = ((unsigned)(c * 2) << 5) | (unsigned)colk;
        unsigned id1 = id0 + 32;
#pragma unroll
        for (int r = 0; r < 16; ++r) {
            float sc0 = fmaf(fr[r], acc0[r], kn0);
            unsigned pz = (__float_as_uint(sc0) & ~1023u) | id0;
            unsigned n2 = med3u(pk1[r], pk2[r], pz);
            unsigned n3 = med3u(pk2[r], pk3[r], pz);
            pk1[r] = umn(pk1[r], pz); pk2[r] = n2; pk3[r] = n3;
            float sc1 = fmaf(fr[r], acc1[r], kn1);
            pz = (__float_as_uint(sc1) & ~1023u) | id1;
            n2 = med3u(pk1[r], pk2[r], pz);
            n3 = med3u(pk2[r], pk3[r], pz);
            pk1[r] = umn(pk1[r], pz); pk2[r] = n2; pk3[r] = n3;
        }

        // write next chunk into the other buffer, then ONE barrier
        if (c < 15) {
#pragma unroll
            for (int r = 0; r < 4; ++r) bbuf[cb ^ 1][r * 512 + t] = stg[r];
        }
        __syncthreads();
    }

    // ---- epilogue: packed-list butterfly over the 32 colk lanes; writers store top-3 ----
#pragma unroll
    for (int r = 0; r < 16; ++r) {
        unsigned a1w = pk1[r], a2w = pk2[r], a3w = pk3[r];
#pragma unroll
        for (int mask = 1; mask < 32; mask <<= 1) {
            unsigned b1 = (unsigned)__shfl_xor((int)a1w, mask, 64);
            unsigned b2 = (unsigned)__shfl_xor((int)a2w, mask, 64);
            unsigned b3 = (unsigned)__shfl_xor((int)a3w, mask, 64);
            unsigned x1 = umn(a1w, b1), y1 = umx(a1w, b1);
            unsigned x2 = umn(a2w, b2);
            unsigned z  = umn(a3w, b3);
            a1w = x1;
            a2w = umn(y1, x2);
            a3w = umn(umx(y1, x2), z);
        }
        if (colk == 0) {
            int pix = w * 32 + (r & 3) + 8 * (r >> 2) + 4 * h;   // 32x32 C/D row map
            unsigned l1 = a1w & 1023u, l2 = a2w & 1023u, l3 = a3w & 1023u;
            unsigned m1 = (unsigned)(yb * 1024) + l1;            // id IS the local index
            unsigned m2 = (unsigned)(yb * 1024) + l2;
            unsigned m3 = (unsigned)(yb * 1024) + l3;
            size_t o = (size_t)yb * N_ + p0 + pix;
            best12[o] = make_float4(__uint_as_float(a1w & ~1023u), __uint_as_float(m1),
                                    __uint_as_float(a2w & ~1023u), __uint_as_float(m2));
            best3[o]  = make_float2(__uint_as_float(a3w & ~1023u), __uint_as_float(m3));
        }
    }
}

// ---------------- kernel 4: merge 6 cands -> approx-top-3, exact fp32 rescue + heatmap ----------------
// Block = 64 pixels x 4 c-groups (256 thr). Reads fp32 q (NOT fp8): rescue must be exact.
__global__ __launch_bounds__(256) void k_heat(
    const float* __restrict__ q, const float* __restrict__ keys,
    const float* __restrict__ kn, const float* __restrict__ rnorm,
    const float4* __restrict__ best12, const float2* __restrict__ best3,
    float* __restrict__ out)
{
    __shared__ float4 pA[64][5];                 // (d0,d1,d2,h0) x 4 cg (+1 pad)
    __shared__ float4 pB[64][5];                 // (h1,h2,-,-)
    int t = threadIdx.x;
    int pl = t & 63, cg = t >> 6;
    int p0 = blockIdx.x * 64;
    int p = p0 + pl;
    const float* qb = q + (size_t)(p / HW_) * (D_ * HW_) + (p % HW_);

    // gather the 2 halves' top-3 lists, merge to approx-top-3 (redundant per cg)
    float4 eA = best12[p];          float2 eA3 = best3[p];
    float4 eB = best12[N_ + p];     float2 eB3 = best3[N_ + p];
    float s1 = eA.x, s2 = eA.z, s3 = eA3.x;
    unsigned i1 = __float_as_uint(eA.y), i2 = __float_as_uint(eA.w), i3 = __float_as_uint(eA3.y);
    insert3(s1, i1, s2, i2, s3, i3, eB.x,  __float_as_uint(eB.y));
    insert3(s1, i1, s2, i2, s3, i3, eB.z,  __float_as_uint(eB.w));
    insert3(s1, i1, s2, i2, s3, i3, eB3.x, __float_as_uint(eB3.y));
    unsigned ci[3] = { i1, i2, i3 };

    float rn = rnorm[p];
    const float* kp0 = keys + (size_t)ci[0] * D_;
    const float* kp1 = keys + (size_t)ci[1] * D_;
    const float* kp2 = keys + (size_t)ci[2] * D_;
    float d0 = 0.f, d1 = 0.f, d2 = 0.f, h0 = 0.f, h1 = 0.f, h2 = 0.f;
    for (int c = cg * 128; c < cg * 128 + 128; c += 4) {
        float qv[4];
#pragma unroll
        for (int j = 0; j < 4; ++j) qv[j] = qb[(size_t)(c + j) * HW_] * rn;  // coalesced
        float4 k0 = *(const float4*)(kp0 + c);
        float4 k1 = *(const float4*)(kp1 + c);
        float4 k2 = *(const float4*)(kp2 + c);
        d0 += qv[0] * k0.x + qv[1] * k0.y + qv[2] * k0.z + qv[3] * k0.w;
        d1 += qv[0] * k1.x + qv[1] * k1.y + qv[2] * k1.z + qv[3] * k1.w;
        d2 += qv[0] * k2.x + qv[1] * k2.y + qv[2] * k2.z + qv[3] * k2.w;
#pragma unroll
        for (int j = 0; j < 4; ++j) {
            float kj0 = ((const float*)&k0)[j], kj1 = ((const float*)&k1)[j], kj2 = ((const float*)&k2)[j];
            float a = qv[j] - kj0, b = qv[j] - kj1, cc = qv[j] - kj2;
            float a2 = a * a, b2 = b * b, c2 = cc * cc;
            h0 += a2 * a2; h1 += b2 * b2; h2 += c2 * c2;
        }
    }
    pA[pl][cg] = make_float4(d0, d1, d2, h0);
    pB[pl][cg] = make_float4(h1, h2, 0.f, 0.f);
    __syncthreads();
    if (t < 64) {                                // cg==0 thread for pixel t holds ci[]
        float D0 = 0.f, D1 = 0.f, D2 = 0.f, H0 = 0.f, H1 = 0.f, H2 = 0.f;
#pragma unroll
        for (int g = 0; g < 4; ++g) {
            float4 a = pA[t][g], b = pB[t][g];
            D0 += a.x; D1 += a.y; D2 += a.z; H0 += a.w; H1 += b.x; H2 += b.y;
        }
        float sA = kn[ci[0]] - 2.0f * D0;
        float sB = kn[ci[1]] - 2.0f * D1;
        float sC = kn[ci[2]] - 2.0f * D2;
        // exact argmin among candidates; tie -> smaller index
        float bs = sA; unsigned bi = ci[0]; float bh = H0;
        if (sB < bs || (sB == bs && ci[1] < bi)) { bs = sB; bi = ci[1]; bh = H1; }
        if (sC < bs || (sC == bs && ci[2] < bi)) { bs = sC; bi = ci[2]; bh = H2; }
        out[p0 + t] = bh;
    }
}

extern "C" void kernel_launch(void* const* d_in, const int* in_sizes, int n_in,
                              void* d_out, int out_size, void* d_ws, size_t ws_size,
                              hipStream_t stream) {
    const float* query = (const float*)d_in[0];   // (8,512,64,64) f32
    const float* keys  = (const float*)d_in[1];   // (2000,512) f32
    float* out = (float*)d_out;                   // 32768 f32

    // workspace layout (~20 MB):
    char* ws = (char*)d_ws;
    unsigned char* qsw8 = (unsigned char*)ws;                        // N*D fp8   = 16.8 MB
    unsigned char* ksw8 = qsw8 + (size_t)N_ * D_;                    // MP*D fp8  = 1 MB
    float*  rnorm  = (float*)(ksw8 + (size_t)MP_ * D_);
    float*  kn     = rnorm + N_;
    float4* best12 = (float4*)(kn + MP_);                            // 2*N float4 = 1 MB
    float2* best3  = (float2*)(best12 + 2 * (size_t)N_);             // 2*N float2 = 0.5 MB

    k_keys<<<MP_ / 4,           256, 0, stream>>>(keys, kn, ksw8);
    k_prep<<<N_ / 64,           256, 0, stream>>>(query, rnorm, qsw8);
    k_mfma<<<dim3(N_ / 256, 2), 512, 0, stream>>>(qsw8, ksw8, kn, rnorm, best12, best3);
    k_heat<<<N_ / 64,           256, 0, stream>>>(query, keys, kn, rnorm, best12, best3, out);
}